// Round 10
// baseline (349.276 us; speedup 1.0000x reference)
//
#include <hip/hip_runtime.h>

#define NN 100000
#define NE 1600000
#define DF 128
#define NG 512
#define NC 10
#define NBK 256
#define NPBN 391       // nodes per bucket = ceil(NN/NBK); last bucket has 295
#define BKCAP 8192     // pairs capacity per bucket (mean 6250, sigma ~79)
#define PCH 4096       // edges per partition block

typedef unsigned short u16;
typedef unsigned int u32;
typedef __bf16 bf16_t;
typedef bf16_t bf16x8 __attribute__((ext_vector_type(8)));
typedef float f32x4 __attribute__((ext_vector_type(4)));

__device__ __forceinline__ u16 f2bf(float f){
  u32 x=__float_as_uint(f);
  u32 r=(x+0x7fffu+((x>>16)&1u))>>16;
  return (u16)r;
}
__device__ __forceinline__ float bflo(u32 u){ return __uint_as_float(u<<16); }
__device__ __forceinline__ float bfhi(u32 u){ return __uint_as_float(u&0xffff0000u); }

// gather-aggregate one node's neighbor rows (lane holds 2 cols as u32)
__device__ __forceinline__ void agg_node(const u32* __restrict__ hv, const int* __restrict__ csr,
                                         int e, int e1, int lane, float& ax, float& ay){
  for(; e+16<=e1; e+=16){
    int ii[16];
    #pragma unroll
    for(int j=0;j<16;++j) ii[j]=csr[e+j];
    u32 vv[16];
    #pragma unroll
    for(int j=0;j<16;++j) vv[j]=hv[(size_t)ii[j]*64+lane];
    #pragma unroll
    for(int j=0;j<16;++j){ ax+=bflo(vv[j]); ay+=bfhi(vv[j]); }
  }
  if(e+8<=e1){
    int ii[8];
    #pragma unroll
    for(int j=0;j<8;++j) ii[j]=csr[e+j];
    u32 vv[8];
    #pragma unroll
    for(int j=0;j<8;++j) vv[j]=hv[(size_t)ii[j]*64+lane];
    #pragma unroll
    for(int j=0;j<8;++j){ ax+=bflo(vv[j]); ay+=bfhi(vv[j]); }
    e+=8;
  }
  if(e+4<=e1){
    int i0=csr[e],i1=csr[e+1],i2=csr[e+2],i3=csr[e+3];
    u32 v0=hv[(size_t)i0*64+lane], v1=hv[(size_t)i1*64+lane];
    u32 v2=hv[(size_t)i2*64+lane], v3=hv[(size_t)i3*64+lane];
    ax+=bflo(v0)+bflo(v1)+bflo(v2)+bflo(v3);
    ay+=bfhi(v0)+bfhi(v1)+bfhi(v2)+bfhi(v3);
    e+=4;
  }
  if(e+2<=e1){
    int i0=csr[e],i1=csr[e+1];
    u32 v0=hv[(size_t)i0*64+lane], v1=hv[(size_t)i1*64+lane];
    ax+=bflo(v0)+bflo(v1);
    ay+=bfhi(v0)+bfhi(v1);
    e+=2;
  }
  if(e<e1){
    u32 v=hv[(size_t)csr[e]*64+lane];
    ax+=bflo(v); ay+=bfhi(v);
  }
}

// fused setup: zero cur[NBK], prep W->WT bf16, goff binary search
__global__ void k_setup(int* __restrict__ cur,
                        const float* __restrict__ W0, const float* __restrict__ W1,
                        const float* __restrict__ W2, u16* __restrict__ WT,
                        const int* __restrict__ batch, int* __restrict__ goff){
  int i=blockIdx.x*256+threadIdx.x;
  if(i<NBK) cur[i]=0;
  if(i<3*DF*DF){
    int w=i>>14, r=i&16383;
    const float* W = (w==0)?W0:((w==1)?W1:W2);
    int k=r>>7, n=r&127;
    WT[(size_t)w*DF*DF + n*128+k]=f2bf(W[r]);
  }
  if(i<=NG){
    int lo=0, hi=NN;
    while(lo<hi){ int mid=(lo+hi)>>1; if(batch[mid]<i) lo=mid+1; else hi=mid; }
    goff[i]=lo;
  }
}

// partition edges into 256 dst-range buckets; NO per-edge global atomics
__global__ __launch_bounds__(256) void k_part(const int* __restrict__ esrc, const int* __restrict__ edst,
                                              int* __restrict__ cur, uint2* __restrict__ pairs, int n){
  __shared__ int hist[NBK], basev[NBK], lscan[NBK], lcur[NBK];
  __shared__ uint2 stage[PCH];   // 32 KB
  int tid=threadIdx.x;
  int start=blockIdx.x*PCH, end=min(start+PCH,n);
  if(tid<NBK) hist[tid]=0;
  __syncthreads();
  for(int i=start+tid;i<end;i+=256) atomicAdd(&hist[(u32)edst[i]/NPBN],1);
  __syncthreads();
  if(tid<64){
    int carry=0;
    #pragma unroll
    for(int c=0;c<NBK;c+=64){
      int v=hist[c+tid], x=v;
      #pragma unroll
      for(int off=1;off<64;off<<=1){ int t=__shfl_up(x,off,64); if(tid>=off) x+=t; }
      lscan[c+tid]=x-v+carry;
      carry+=__shfl(x,63,64);
    }
  }
  __syncthreads();
  if(tid<NBK){ basev[tid]=atomicAdd(&cur[tid],hist[tid]); lcur[tid]=0; }
  __syncthreads();
  for(int i=start+tid;i<end;i+=256){
    int d=edst[i], s=esrc[i];
    int b=(u32)d/NPBN;
    int p=lscan[b]+atomicAdd(&lcur[b],1);
    stage[p]=make_uint2((u32)s,(u32)d);
  }
  __syncthreads();
  int ntot=end-start;
  for(int i=tid;i<ntot;i+=256){
    uint2 e=stage[i];
    int b=(u32)e.y/NPBN;
    pairs[(size_t)b*BKCAP + basev[b] + (i - lscan[b])]=e;
  }
}

// one block per bucket: local histogram -> offs/dinv -> place csr (L2-local window)
__global__ __launch_bounds__(256) void k_bucket(const uint2* __restrict__ pairs, const int* __restrict__ cur,
                                                int* __restrict__ offs, float* __restrict__ dinv,
                                                int* __restrict__ csr){
  __shared__ int hist[NPBN], lsc[NPBN], curL[NBK];
  __shared__ int sbase[2];
  int b=blockIdx.x, tid=threadIdx.x;
  if(tid<NBK) curL[tid]=cur[tid];
  for(int j=tid;j<NPBN;j+=256) hist[j]=0;
  __syncthreads();
  if(tid<64){
    int acc=0;
    #pragma unroll
    for(int c=0;c<NBK;c+=64){
      int v=(c+tid<b)? curL[c+tid] : 0;
      #pragma unroll
      for(int off=32;off;off>>=1) v+=__shfl_xor(v,off,64);
      acc+=v;
    }
    if(tid==0){ sbase[0]=acc; sbase[1]=curL[b]; }
  }
  __syncthreads();
  int base=sbase[0], count=sbase[1];
  int node0=b*NPBN;
  int nnode=min(NPBN, NN-node0);
  const uint2* P=pairs+(size_t)b*BKCAP;
  for(int i=tid;i<count;i+=256) atomicAdd(&hist[P[i].y-node0],1);
  __syncthreads();
  if(tid<64){
    int carry=0;
    #pragma unroll
    for(int c=0;c<448;c+=64){
      int idx=c+tid;
      int v=(idx<NPBN)? hist[idx] : 0, x=v;
      #pragma unroll
      for(int off=1;off<64;off<<=1){ int t=__shfl_up(x,off,64); if(tid>=off) x+=t; }
      if(idx<NPBN) lsc[idx]=x-v+carry;
      carry+=__shfl(x,63,64);
    }
  }
  __syncthreads();
  for(int j=tid;j<nnode;j+=256){
    offs[node0+j]=base+lsc[j];
    dinv[node0+j]=rsqrtf((float)hist[j]+1.0f);
  }
  if(b==NBK-1 && tid==0) offs[NN]=base+count;
  __syncthreads();
  for(int j=tid;j<nnode;j+=256) hist[j]=lsc[j];
  __syncthreads();
  for(int i=tid;i<count;i+=256){
    uint2 e=P[i];
    int p=atomicAdd(&hist[e.y-node0],1);
    csr[base+p]=(int)e.x;
  }
}

// layer-0 GEMM: out[row][c] = bf16( dinv[row] * sum_k x[row][k]*W[k][c] ), x fp32
__global__ __launch_bounds__(256) void k_gemm0(const float* __restrict__ A, const u16* __restrict__ WT,
                                               const float* __restrict__ dinv, u16* __restrict__ outp, int n){
  __shared__ u16 sA[128][136];
  __shared__ u16 sW[128][136];
  int tid=threadIdx.x;
  int row0=blockIdx.x*128;
  {
    const uint4* p=(const uint4*)WT;
    #pragma unroll
    for(int j=0;j<8;++j){
      int c=tid+j*256;
      int r=c>>4, c8=c&15;
      *(uint4*)&sW[r][c8*8]=p[c];
    }
  }
  {
    const float4* A4=(const float4*)A;
    #pragma unroll
    for(int j=0;j<16;++j){
      int c=tid+j*256;
      int r=c>>5, c4=c&31;
      int row=row0+r;
      float4 v = (row<n)? A4[(size_t)row*32+c4] : make_float4(0.f,0.f,0.f,0.f);
      u32 lo=(u32)f2bf(v.x) | ((u32)f2bf(v.y)<<16);
      u32 hi=(u32)f2bf(v.z) | ((u32)f2bf(v.w)<<16);
      uint2 q; q.x=lo; q.y=hi;
      *(uint2*)&sA[r][c4*4]=q;
    }
  }
  __syncthreads();
  int wv=tid>>6, lane=tid&63;
  int lr=lane&15, lk=lane>>4;
  f32x4 acc[2][8];
  #pragma unroll
  for(int mr=0;mr<2;++mr)
    #pragma unroll
    for(int nt=0;nt<8;++nt) acc[mr][nt]=(f32x4){0.f,0.f,0.f,0.f};
  #pragma unroll
  for(int kk=0;kk<4;++kk){
    bf16x8 a[2], b[8];
    #pragma unroll
    for(int mr=0;mr<2;++mr)
      a[mr]=*(const bf16x8*)&sA[wv*32+mr*16+lr][kk*32+lk*8];
    #pragma unroll
    for(int nt=0;nt<8;++nt)
      b[nt]=*(const bf16x8*)&sW[nt*16+lr][kk*32+lk*8];
    #pragma unroll
    for(int mr=0;mr<2;++mr)
      #pragma unroll
      for(int nt=0;nt<8;++nt)
        acc[mr][nt]=__builtin_amdgcn_mfma_f32_16x16x32_bf16(a[mr],b[nt],acc[mr][nt],0,0,0);
  }
  #pragma unroll
  for(int mr=0;mr<2;++mr){
    int rbase=row0+wv*32+mr*16+lk*4;
    #pragma unroll
    for(int r=0;r<4;++r){
      int row=rbase+r;
      if(row<n){
        float di=dinv[row];
        #pragma unroll
        for(int nt=0;nt<8;++nt)
          outp[(size_t)row*128+nt*16+lr]=f2bf(acc[mr][nt][r]*di);
      }
    }
  }
}

// fused agg + GEMM: h = relu(dinv*(gather h2in)+bias) in LDS, then out = bf16(dinv*(h@W))
__global__ __launch_bounds__(512) void k_fuse(const u16* __restrict__ h2in, const int* __restrict__ offs,
                                              const int* __restrict__ csr, const float* __restrict__ dinv,
                                              const float* __restrict__ biasv, const u16* __restrict__ WT,
                                              u16* __restrict__ outp, int n){
  __shared__ u16 sA[128][136];
  __shared__ u16 sW[128][136];
  int tid=threadIdx.x;
  int row0=blockIdx.x*128;
  {
    const uint4* p=(const uint4*)WT;
    #pragma unroll
    for(int j=0;j<4;++j){
      int c=tid+j*512;
      int r=c>>4, c8=c&15;
      *(uint4*)&sW[r][c8*8]=p[c];
    }
  }
  int wid=tid>>6, lane=tid&63;
  const u32* hv=(const u32*)h2in;
  float2 bv=*(const float2*)&biasv[lane*2];
  // gather phase: wave wid aggregates 16 nodes into sA rows
  for(int k=0;k<16;++k){
    int local=wid*16+k;
    int node=row0+local;
    u32 oword=0;
    if(node<n){
      u32 sv=hv[(size_t)node*64+lane];
      float ax=bflo(sv), ay=bfhi(sv);
      agg_node(hv, csr, offs[node], offs[node+1], lane, ax, ay);
      float di=dinv[node];
      float ox=fmaf(di,ax,bv.x), oy=fmaf(di,ay,bv.y);
      ox=ox>0.f?ox:0.f; oy=oy>0.f?oy:0.f;
      oword=(u32)f2bf(ox) | ((u32)f2bf(oy)<<16);
    }
    *(u32*)&sA[local][lane*2]=oword;
  }
  __syncthreads();
  // MFMA phase: 8 waves, wave wid owns rows [wid*16, wid*16+16)
  int lr=lane&15, lk=lane>>4;
  f32x4 acc[8];
  #pragma unroll
  for(int nt=0;nt<8;++nt) acc[nt]=(f32x4){0.f,0.f,0.f,0.f};
  #pragma unroll
  for(int kk=0;kk<4;++kk){
    bf16x8 a=*(const bf16x8*)&sA[wid*16+lr][kk*32+lk*8];
    bf16x8 b[8];
    #pragma unroll
    for(int nt=0;nt<8;++nt)
      b[nt]=*(const bf16x8*)&sW[nt*16+lr][kk*32+lk*8];
    #pragma unroll
    for(int nt=0;nt<8;++nt)
      acc[nt]=__builtin_amdgcn_mfma_f32_16x16x32_bf16(a,b[nt],acc[nt],0,0,0);
  }
  int rbase=row0+wid*16+lk*4;
  #pragma unroll
  for(int r=0;r<4;++r){
    int row=rbase+r;
    if(row<n){
      float di=dinv[row];
      #pragma unroll
      for(int nt=0;nt<8;++nt)
        outp[(size_t)row*128+nt*16+lr]=f2bf(acc[nt][r]*di);
    }
  }
}

// final (unfused) aggregation: out = bf16(relu(dinv*(gather)+b))
__global__ __launch_bounds__(256) void k_agg(const u16* __restrict__ h2, const int* __restrict__ offs,
                                             const int* __restrict__ csr, const float* __restrict__ dinv,
                                             const float* __restrict__ bias, u16* __restrict__ outp, int n){
  int wid=threadIdx.x>>6, lane=threadIdx.x&63;
  int node=blockIdx.x*4+wid;
  if(node>=n) return;
  const u32* hv=(const u32*)h2;
  u32 sv=hv[(size_t)node*64+lane];
  float ax=bflo(sv), ay=bfhi(sv);
  agg_node(hv, csr, offs[node], offs[node+1], lane, ax, ay);
  float di=dinv[node];
  float2 b=*(const float2*)&bias[lane*2];
  float ox=fmaf(di,ax,b.x), oy=fmaf(di,ay,b.y);
  ox=ox>0.f?ox:0.f; oy=oy>0.f?oy:0.f;
  u32 o=(u32)f2bf(ox) | ((u32)f2bf(oy)<<16);
  ((u32*)outp)[(size_t)node*64+lane]=o;
}

// 8-wave pooling: wave w strides rows, lane loads u32 (2 cols); LDS reduce + matvec
__global__ __launch_bounds__(512) void k_pool(const u16* __restrict__ h, const int* __restrict__ goff,
                                              const float* __restrict__ Wc, const float* __restrict__ bc,
                                              float* __restrict__ outp){
  __shared__ float part[8][128];
  __shared__ float pooled[128];
  int g=blockIdx.x;
  int tid=threadIdx.x, wid=tid>>6, lane=tid&63;
  int i0=goff[g], i1=goff[g+1];
  const u32* hv=(const u32*)h;
  float ax=0.f, ay=0.f;
  for(int i=i0+wid;i<i1;i+=8){
    u32 v=hv[(size_t)i*64+lane];
    ax+=bflo(v); ay+=bfhi(v);
  }
  part[wid][lane*2]=ax; part[wid][lane*2+1]=ay;
  __syncthreads();
  if(tid<128){
    float s=part[0][tid]+part[1][tid]+part[2][tid]+part[3][tid]
           +part[4][tid]+part[5][tid]+part[6][tid]+part[7][tid];
    int cnt=i1-i0;
    pooled[tid]=(cnt>0)? s/(float)cnt : 0.f;
  }
  __syncthreads();
  if(tid<NC){
    float s=bc[tid];
    #pragma unroll 16
    for(int k=0;k<128;++k) s=fmaf(pooled[k], Wc[k*NC+tid], s);
    outp[g*NC+tid]=s;
  }
}

extern "C" void kernel_launch(void* const* d_in, const int* in_sizes, int n_in,
                              void* d_out, int out_size, void* d_ws, size_t ws_size,
                              hipStream_t stream){
  const float* x   =(const float*)d_in[0];
  const int* esrc  =(const int*)d_in[1];
  const int* edst  =(const int*)d_in[2];
  const int* batch =(const int*)d_in[3];
  const float* W0=(const float*)d_in[4];
  const float* b0=(const float*)d_in[5];
  const float* W1=(const float*)d_in[6];
  const float* b1=(const float*)d_in[7];
  const float* W2=(const float*)d_in[8];
  const float* b2=(const float*)d_in[9];
  const float* Wc=(const float*)d_in[10];
  const float* bc=(const float*)d_in[11];
  float* out=(float*)d_out;

  char* base=(char*)d_ws; size_t off=0;
  auto alloc=[&](size_t bytes)->void*{ off=(off+255)&~(size_t)255; void* p=base+off; off+=bytes; return p; };
  int*   cur  =(int*)  alloc(NBK*4);
  int*   offs =(int*)  alloc((size_t)(NN+1)*4);
  int*   goff =(int*)  alloc((NG+1)*4);
  float* dinv =(float*)alloc((size_t)NN*4);
  int*   csr  =(int*)  alloc((size_t)NE*4);
  uint2* pairs=(uint2*)alloc((size_t)NBK*BKCAP*8);
  u16*   WT   =(u16*)  alloc((size_t)3*DF*DF*2);
  u16*   bufA =(u16*)  alloc((size_t)NN*DF*2);
  u16*   bufB =(u16*)  alloc((size_t)NN*DF*2);
  (void)ws_size; (void)in_sizes; (void)n_in; (void)out_size;

  hipLaunchKernelGGL(k_setup,  dim3(192),  dim3(256), 0, stream, cur, W0, W1, W2, WT, batch, goff);
  hipLaunchKernelGGL(k_part,   dim3((NE+PCH-1)/PCH), dim3(256), 0, stream, esrc, edst, cur, pairs, NE);
  hipLaunchKernelGGL(k_bucket, dim3(NBK),  dim3(256), 0, stream, pairs, cur, offs, dinv, csr);

  const int GB=(NN+127)/128;    // 782
  const int AB=(NN+3)/4;        // 25000

  hipLaunchKernelGGL(k_gemm0, dim3(GB), dim3(256), 0, stream, x, WT, dinv, bufA, NN);
  hipLaunchKernelGGL(k_fuse,  dim3(GB), dim3(512), 0, stream, bufA, offs, csr, dinv, b0, WT+DF*DF,   bufB, NN);
  hipLaunchKernelGGL(k_fuse,  dim3(GB), dim3(512), 0, stream, bufB, offs, csr, dinv, b1, WT+2*DF*DF, bufA, NN);
  hipLaunchKernelGGL(k_agg,   dim3(AB), dim3(256), 0, stream, bufA, offs, csr, dinv, b2, bufB, NN);
  hipLaunchKernelGGL(k_pool,  dim3(NG), dim3(512), 0, stream, bufB, goff, Wc, bc, out);
}

// Round 11
// 328.083 us; speedup vs baseline: 1.0646x; 1.0646x over previous
//
#include <hip/hip_runtime.h>

#define NN 100000
#define NE 1600000
#define DF 128
#define NG 512
#define NC 10
#define NBK 256
#define NPBN 391       // nodes per bucket = ceil(NN/NBK)
#define BKCAP 8192     // pairs capacity per bucket (mean 6250, sigma ~79)
#define PCH 4096       // edges per partition block
#define POOLSLOT 6     // graph segments a 64-node block can touch (worst case ~3)

typedef unsigned short u16;
typedef unsigned int u32;
typedef __bf16 bf16_t;
typedef bf16_t bf16x8 __attribute__((ext_vector_type(8)));
typedef float f32x4 __attribute__((ext_vector_type(4)));

__device__ __forceinline__ u16 f2bf(float f){
  u32 x=__float_as_uint(f);
  u32 r=(x+0x7fffu+((x>>16)&1u))>>16;
  return (u16)r;
}
__device__ __forceinline__ float bflo(u32 u){ return __uint_as_float(u<<16); }
__device__ __forceinline__ float bfhi(u32 u){ return __uint_as_float(u&0xffff0000u); }

// gather-aggregate one node's neighbor rows (lane holds 2 cols as u32)
__device__ __forceinline__ void agg_node(const u32* __restrict__ hv, const int* __restrict__ csr,
                                         int e, int e1, int lane, float& ax, float& ay){
  for(; e+16<=e1; e+=16){
    int ii[16];
    #pragma unroll
    for(int j=0;j<16;++j) ii[j]=csr[e+j];
    u32 vv[16];
    #pragma unroll
    for(int j=0;j<16;++j) vv[j]=hv[(size_t)ii[j]*64+lane];
    #pragma unroll
    for(int j=0;j<16;++j){ ax+=bflo(vv[j]); ay+=bfhi(vv[j]); }
  }
  if(e+8<=e1){
    int ii[8];
    #pragma unroll
    for(int j=0;j<8;++j) ii[j]=csr[e+j];
    u32 vv[8];
    #pragma unroll
    for(int j=0;j<8;++j) vv[j]=hv[(size_t)ii[j]*64+lane];
    #pragma unroll
    for(int j=0;j<8;++j){ ax+=bflo(vv[j]); ay+=bfhi(vv[j]); }
    e+=8;
  }
  if(e+4<=e1){
    int i0=csr[e],i1=csr[e+1],i2=csr[e+2],i3=csr[e+3];
    u32 v0=hv[(size_t)i0*64+lane], v1=hv[(size_t)i1*64+lane];
    u32 v2=hv[(size_t)i2*64+lane], v3=hv[(size_t)i3*64+lane];
    ax+=bflo(v0)+bflo(v1)+bflo(v2)+bflo(v3);
    ay+=bfhi(v0)+bfhi(v1)+bfhi(v2)+bfhi(v3);
    e+=4;
  }
  if(e+2<=e1){
    int i0=csr[e],i1=csr[e+1];
    u32 v0=hv[(size_t)i0*64+lane], v1=hv[(size_t)i1*64+lane];
    ax+=bflo(v0)+bflo(v1);
    ay+=bfhi(v0)+bfhi(v1);
    e+=2;
  }
  if(e<e1){
    u32 v=hv[(size_t)csr[e]*64+lane];
    ax+=bflo(v); ay+=bfhi(v);
  }
}

// fused setup: zero cur[NBK] + pooled[NG*128], prep W->WT bf16, goff binary search
__global__ void k_setup(int* __restrict__ cur, float* __restrict__ pooled,
                        const float* __restrict__ W0, const float* __restrict__ W1,
                        const float* __restrict__ W2, u16* __restrict__ WT,
                        const int* __restrict__ batch, int* __restrict__ goff){
  int i=blockIdx.x*256+threadIdx.x;   // grid 256 -> 65536 threads
  if(i<NBK) cur[i]=0;
  if(i<NG*DF) pooled[i]=0.f;
  if(i<3*DF*DF){
    int w=i>>14, r=i&16383;
    const float* W = (w==0)?W0:((w==1)?W1:W2);
    int k=r>>7, n=r&127;
    WT[(size_t)w*DF*DF + n*128+k]=f2bf(W[r]);
  }
  if(i<=NG){
    int lo=0, hi=NN;
    while(lo<hi){ int mid=(lo+hi)>>1; if(batch[mid]<i) lo=mid+1; else hi=mid; }
    goff[i]=lo;
  }
}

// partition edges into 256 dst-range buckets; NO per-edge global atomics
__global__ __launch_bounds__(256) void k_part(const int* __restrict__ esrc, const int* __restrict__ edst,
                                              int* __restrict__ cur, uint2* __restrict__ pairs, int n){
  __shared__ int hist[NBK], basev[NBK], lscan[NBK], lcur[NBK];
  __shared__ uint2 stage[PCH];   // 32 KB
  int tid=threadIdx.x;
  int start=blockIdx.x*PCH, end=min(start+PCH,n);
  if(tid<NBK) hist[tid]=0;
  __syncthreads();
  for(int i=start+tid;i<end;i+=256) atomicAdd(&hist[(u32)edst[i]/NPBN],1);
  __syncthreads();
  if(tid<64){
    int carry=0;
    #pragma unroll
    for(int c=0;c<NBK;c+=64){
      int v=hist[c+tid], x=v;
      #pragma unroll
      for(int off=1;off<64;off<<=1){ int t=__shfl_up(x,off,64); if(tid>=off) x+=t; }
      lscan[c+tid]=x-v+carry;
      carry+=__shfl(x,63,64);
    }
  }
  __syncthreads();
  if(tid<NBK){ basev[tid]=atomicAdd(&cur[tid],hist[tid]); lcur[tid]=0; }
  __syncthreads();
  for(int i=start+tid;i<end;i+=256){
    int d=edst[i], s=esrc[i];
    int b=(u32)d/NPBN;
    int p=lscan[b]+atomicAdd(&lcur[b],1);
    stage[p]=make_uint2((u32)s,(u32)d);
  }
  __syncthreads();
  int ntot=end-start;
  for(int i=tid;i<ntot;i+=256){
    uint2 e=stage[i];
    int b=(u32)e.y/NPBN;
    pairs[(size_t)b*BKCAP + basev[b] + (i - lscan[b])]=e;
  }
}

// one block per bucket: local histogram -> offs/dinv -> place csr (L2-local window)
__global__ __launch_bounds__(256) void k_bucket(const uint2* __restrict__ pairs, const int* __restrict__ cur,
                                                int* __restrict__ offs, float* __restrict__ dinv,
                                                int* __restrict__ csr){
  __shared__ int hist[NPBN], lsc[NPBN], curL[NBK];
  __shared__ int sbase[2];
  int b=blockIdx.x, tid=threadIdx.x;
  if(tid<NBK) curL[tid]=cur[tid];
  for(int j=tid;j<NPBN;j+=256) hist[j]=0;
  __syncthreads();
  if(tid<64){
    int acc=0;
    #pragma unroll
    for(int c=0;c<NBK;c+=64){
      int v=(c+tid<b)? curL[c+tid] : 0;
      #pragma unroll
      for(int off=32;off;off>>=1) v+=__shfl_xor(v,off,64);
      acc+=v;
    }
    if(tid==0){ sbase[0]=acc; sbase[1]=curL[b]; }
  }
  __syncthreads();
  int base=sbase[0], count=sbase[1];
  int node0=b*NPBN;
  int nnode=min(NPBN, NN-node0);
  const uint2* P=pairs+(size_t)b*BKCAP;
  for(int i=tid;i<count;i+=256) atomicAdd(&hist[P[i].y-node0],1);
  __syncthreads();
  if(tid<64){
    int carry=0;
    #pragma unroll
    for(int c=0;c<448;c+=64){
      int idx=c+tid;
      int v=(idx<NPBN)? hist[idx] : 0, x=v;
      #pragma unroll
      for(int off=1;off<64;off<<=1){ int t=__shfl_up(x,off,64); if(tid>=off) x+=t; }
      if(idx<NPBN) lsc[idx]=x-v+carry;
      carry+=__shfl(x,63,64);
    }
  }
  __syncthreads();
  for(int j=tid;j<nnode;j+=256){
    offs[node0+j]=base+lsc[j];
    dinv[node0+j]=rsqrtf((float)hist[j]+1.0f);
  }
  if(b==NBK-1 && tid==0) offs[NN]=base+count;
  __syncthreads();
  for(int j=tid;j<nnode;j+=256) hist[j]=lsc[j];
  __syncthreads();
  for(int i=tid;i<count;i+=256){
    uint2 e=P[i];
    int p=atomicAdd(&hist[e.y-node0],1);
    csr[base+p]=(int)e.x;
  }
}

// out[row][c] = bf16( dinv[row] * sum_k A[row][k]*W[k][c] ), MFMA bf16
template<bool F32IN>
__global__ __launch_bounds__(256) void k_gemm(const void* __restrict__ Ap, const u16* __restrict__ WT,
                                              const float* __restrict__ dinv, u16* __restrict__ outp, int n){
  __shared__ u16 sA[128][136];
  __shared__ u16 sW[128][136];
  int tid=threadIdx.x;
  int row0=blockIdx.x*128;
  {
    const uint4* p=(const uint4*)WT;
    #pragma unroll
    for(int j=0;j<8;++j){
      int c=tid+j*256;
      int r=c>>4, c8=c&15;
      *(uint4*)&sW[r][c8*8]=p[c];
    }
  }
  if(F32IN){
    const float4* A4=(const float4*)Ap;
    #pragma unroll
    for(int j=0;j<16;++j){
      int c=tid+j*256;
      int r=c>>5, c4=c&31;
      int row=row0+r;
      float4 v = (row<n)? A4[(size_t)row*32+c4] : make_float4(0.f,0.f,0.f,0.f);
      u32 lo=(u32)f2bf(v.x) | ((u32)f2bf(v.y)<<16);
      u32 hi=(u32)f2bf(v.z) | ((u32)f2bf(v.w)<<16);
      uint2 q; q.x=lo; q.y=hi;
      *(uint2*)&sA[r][c4*4]=q;
    }
  } else {
    const uint4* A4=(const uint4*)Ap;
    #pragma unroll
    for(int j=0;j<8;++j){
      int c=tid+j*256;
      int r=c>>4, c8=c&15;
      int row=row0+r;
      uint4 v = (row<n)? A4[(size_t)row*16+c8] : make_uint4(0,0,0,0);
      *(uint4*)&sA[r][c8*8]=v;
    }
  }
  __syncthreads();
  int wv=tid>>6, lane=tid&63;
  int lr=lane&15, lk=lane>>4;
  f32x4 acc[2][8];
  #pragma unroll
  for(int mr=0;mr<2;++mr)
    #pragma unroll
    for(int nt=0;nt<8;++nt) acc[mr][nt]=(f32x4){0.f,0.f,0.f,0.f};
  #pragma unroll
  for(int kk=0;kk<4;++kk){
    bf16x8 a[2], b[8];
    #pragma unroll
    for(int mr=0;mr<2;++mr)
      a[mr]=*(const bf16x8*)&sA[wv*32+mr*16+lr][kk*32+lk*8];
    #pragma unroll
    for(int nt=0;nt<8;++nt)
      b[nt]=*(const bf16x8*)&sW[nt*16+lr][kk*32+lk*8];
    #pragma unroll
    for(int mr=0;mr<2;++mr)
      #pragma unroll
      for(int nt=0;nt<8;++nt)
        acc[mr][nt]=__builtin_amdgcn_mfma_f32_16x16x32_bf16(a[mr],b[nt],acc[mr][nt],0,0,0);
  }
  #pragma unroll
  for(int mr=0;mr<2;++mr){
    int rbase=row0+wv*32+mr*16+lk*4;
    #pragma unroll
    for(int r=0;r<4;++r){
      int row=rbase+r;
      if(row<n){
        float di=dinv[row];
        #pragma unroll
        for(int nt=0;nt<8;++nt)
          outp[(size_t)row*128+nt*16+lr]=f2bf(acc[mr][nt][r]*di);
      }
    }
  }
}

// mid-layer aggregation: out = bf16(relu(dinv*(gather)+b))
__global__ __launch_bounds__(256) void k_agg(const u16* __restrict__ h2, const int* __restrict__ offs,
                                             const int* __restrict__ csr, const float* __restrict__ dinv,
                                             const float* __restrict__ bias, u16* __restrict__ outp, int n){
  int wid=threadIdx.x>>6, lane=threadIdx.x&63;
  int node=blockIdx.x*4+wid;
  if(node>=n) return;
  const u32* hv=(const u32*)h2;
  u32 sv=hv[(size_t)node*64+lane];
  float ax=bflo(sv), ay=bfhi(sv);
  agg_node(hv, csr, offs[node], offs[node+1], lane, ax, ay);
  float di=dinv[node];
  float2 b=*(const float2*)&bias[lane*2];
  float ox=fmaf(di,ax,b.x), oy=fmaf(di,ay,b.y);
  ox=ox>0.f?ox:0.f; oy=oy>0.f?oy:0.f;
  u32 o=(u32)f2bf(ox) | ((u32)f2bf(oy)<<16);
  ((u32*)outp)[(size_t)node*64+lane]=o;
}

// final layer: aggregate + relu, accumulate per-graph sums (no h3 materialization)
__global__ __launch_bounds__(512) void k_aggpool(const u16* __restrict__ h2, const int* __restrict__ offs,
                                                 const int* __restrict__ csr, const float* __restrict__ dinv,
                                                 const float* __restrict__ bias, const int* __restrict__ batch,
                                                 float* __restrict__ pooled, int n){
  __shared__ float accL[POOLSLOT][128];
  __shared__ int smaxL;
  int tid=threadIdx.x, wid=tid>>6, lane=tid&63;
  int row0=blockIdx.x*64;
  if(tid==0) smaxL=0;
  if(tid<128){
    #pragma unroll
    for(int s=0;s<POOLSLOT;++s) accL[s][tid]=0.f;
  }
  __syncthreads();
  if(row0>=n) return;
  int gbase=batch[row0];
  const u32* hv=(const u32*)h2;
  float2 bv=*(const float2*)&bias[lane*2];
  int wmax=0;
  for(int k=0;k<8;++k){
    int node=row0+wid*8+k;
    if(node>=n) break;
    u32 sv=hv[(size_t)node*64+lane];
    float ax=bflo(sv), ay=bfhi(sv);
    agg_node(hv, csr, offs[node], offs[node+1], lane, ax, ay);
    float di=dinv[node];
    float ox=fmaf(di,ax,bv.x), oy=fmaf(di,ay,bv.y);
    ox=ox>0.f?ox:0.f; oy=oy>0.f?oy:0.f;
    int slot=batch[node]-gbase;          // wave-uniform
    if(slot<POOLSLOT){
      atomicAdd(&accL[slot][lane*2],  ox);
      atomicAdd(&accL[slot][lane*2+1],oy);
      wmax=max(wmax,slot);
    }else{                               // practically unreachable safety net
      atomicAdd(&pooled[(size_t)(gbase+slot)*128+lane*2],  ox);
      atomicAdd(&pooled[(size_t)(gbase+slot)*128+lane*2+1],oy);
    }
  }
  if(lane==0) atomicMax(&smaxL,wmax);
  __syncthreads();
  int smax=smaxL;
  if(tid<128){
    for(int s=0;s<=smax;++s){
      float v=accL[s][tid];
      if(v!=0.f) atomicAdd(&pooled[(size_t)(gbase+s)*128+tid],v);
    }
  }
}

// head: out[g] = pooled[g]/max(cnt,1) @ Wc + bc
__global__ __launch_bounds__(128) void k_head(const float* __restrict__ pooled, const int* __restrict__ goff,
                                              const float* __restrict__ Wc, const float* __restrict__ bc,
                                              float* __restrict__ outp){
  __shared__ float pl[128];
  int g=blockIdx.x, d=threadIdx.x;
  int cnt=goff[g+1]-goff[g];
  float s=pooled[(size_t)g*128+d];
  pl[d]=(cnt>0)? s/(float)cnt : 0.f;
  __syncthreads();
  if(d<NC){
    float acc=bc[d];
    #pragma unroll 16
    for(int k=0;k<128;++k) acc=fmaf(pl[k], Wc[k*NC+d], acc);
    outp[g*NC+d]=acc;
  }
}

extern "C" void kernel_launch(void* const* d_in, const int* in_sizes, int n_in,
                              void* d_out, int out_size, void* d_ws, size_t ws_size,
                              hipStream_t stream){
  const float* x   =(const float*)d_in[0];
  const int* esrc  =(const int*)d_in[1];
  const int* edst  =(const int*)d_in[2];
  const int* batch =(const int*)d_in[3];
  const float* W0=(const float*)d_in[4];
  const float* b0=(const float*)d_in[5];
  const float* W1=(const float*)d_in[6];
  const float* b1=(const float*)d_in[7];
  const float* W2=(const float*)d_in[8];
  const float* b2=(const float*)d_in[9];
  const float* Wc=(const float*)d_in[10];
  const float* bc=(const float*)d_in[11];
  float* out=(float*)d_out;

  char* base=(char*)d_ws; size_t off=0;
  auto alloc=[&](size_t bytes)->void*{ off=(off+255)&~(size_t)255; void* p=base+off; off+=bytes; return p; };
  int*   cur   =(int*)  alloc(NBK*4);
  int*   offs  =(int*)  alloc((size_t)(NN+1)*4);
  int*   goff  =(int*)  alloc((NG+1)*4);
  float* dinv  =(float*)alloc((size_t)NN*4);
  int*   csr   =(int*)  alloc((size_t)NE*4);
  uint2* pairs =(uint2*)alloc((size_t)NBK*BKCAP*8);
  u16*   WT    =(u16*)  alloc((size_t)3*DF*DF*2);
  float* pooled=(float*)alloc((size_t)NG*DF*4);
  u16*   bufA  =(u16*)  alloc((size_t)NN*DF*2);
  u16*   bufB  =(u16*)  alloc((size_t)NN*DF*2);
  (void)ws_size; (void)in_sizes; (void)n_in; (void)out_size;

  hipLaunchKernelGGL(k_setup,  dim3(256),  dim3(256), 0, stream, cur, pooled, W0, W1, W2, WT, batch, goff);
  hipLaunchKernelGGL(k_part,   dim3((NE+PCH-1)/PCH), dim3(256), 0, stream, esrc, edst, cur, pairs, NE);
  hipLaunchKernelGGL(k_bucket, dim3(NBK),  dim3(256), 0, stream, pairs, cur, offs, dinv, csr);

  const int GB=(NN+127)/128;    // 782
  const int AB=(NN+3)/4;        // 25000
  const int PB=(NN+63)/64;      // 1563

  k_gemm<true ><<<dim3(GB), dim3(256), 0, stream>>>((const void*)x,    WT,         dinv, bufA, NN);
  hipLaunchKernelGGL(k_agg,  dim3(AB), dim3(256), 0, stream, bufA, offs, csr, dinv, b0, bufB, NN);
  k_gemm<false><<<dim3(GB), dim3(256), 0, stream>>>((const void*)bufB, WT+DF*DF,   dinv, bufA, NN);
  hipLaunchKernelGGL(k_agg,  dim3(AB), dim3(256), 0, stream, bufA, offs, csr, dinv, b1, bufB, NN);
  k_gemm<false><<<dim3(GB), dim3(256), 0, stream>>>((const void*)bufB, WT+2*DF*DF, dinv, bufA, NN);
  hipLaunchKernelGGL(k_aggpool, dim3(PB), dim3(512), 0, stream, bufA, offs, csr, dinv, b2, batch, pooled, NN);
  hipLaunchKernelGGL(k_head, dim3(NG), dim3(128), 0, stream, pooled, goff, Wc, bc, out);
}

// Round 12
// 299.514 us; speedup vs baseline: 1.1661x; 1.0954x over previous
//
#include <hip/hip_runtime.h>

#define NN 100000
#define NE 1600000
#define DF 128
#define NG 512
#define NC 10
#define NBK 256
#define NPBN 391       // nodes per bucket = ceil(NN/NBK)
#define BKCAP 8192     // pairs capacity per bucket (mean 6250, sigma ~79)
#define PCH 4096       // edges per partition block

typedef unsigned short u16;
typedef unsigned int u32;
typedef __bf16 bf16_t;
typedef bf16_t bf16x8 __attribute__((ext_vector_type(8)));
typedef float f32x4 __attribute__((ext_vector_type(4)));

__device__ __forceinline__ u16 f2bf(float f){
  u32 x=__float_as_uint(f);
  u32 r=(x+0x7fffu+((x>>16)&1u))>>16;
  return (u16)r;
}
__device__ __forceinline__ float bflo(u32 u){ return __uint_as_float(u<<16); }
__device__ __forceinline__ float bfhi(u32 u){ return __uint_as_float(u&0xffff0000u); }

// gather-aggregate one node's neighbor rows (lane holds 2 cols as u32)
__device__ __forceinline__ void agg_node(const u32* __restrict__ hv, const int* __restrict__ csr,
                                         int e, int e1, int lane, float& ax, float& ay){
  for(; e+16<=e1; e+=16){
    int ii[16];
    #pragma unroll
    for(int j=0;j<16;++j) ii[j]=csr[e+j];
    u32 vv[16];
    #pragma unroll
    for(int j=0;j<16;++j) vv[j]=hv[(size_t)ii[j]*64+lane];
    #pragma unroll
    for(int j=0;j<16;++j){ ax+=bflo(vv[j]); ay+=bfhi(vv[j]); }
  }
  if(e+8<=e1){
    int ii[8];
    #pragma unroll
    for(int j=0;j<8;++j) ii[j]=csr[e+j];
    u32 vv[8];
    #pragma unroll
    for(int j=0;j<8;++j) vv[j]=hv[(size_t)ii[j]*64+lane];
    #pragma unroll
    for(int j=0;j<8;++j){ ax+=bflo(vv[j]); ay+=bfhi(vv[j]); }
    e+=8;
  }
  if(e+4<=e1){
    int i0=csr[e],i1=csr[e+1],i2=csr[e+2],i3=csr[e+3];
    u32 v0=hv[(size_t)i0*64+lane], v1=hv[(size_t)i1*64+lane];
    u32 v2=hv[(size_t)i2*64+lane], v3=hv[(size_t)i3*64+lane];
    ax+=bflo(v0)+bflo(v1)+bflo(v2)+bflo(v3);
    ay+=bfhi(v0)+bfhi(v1)+bfhi(v2)+bfhi(v3);
    e+=4;
  }
  if(e+2<=e1){
    int i0=csr[e],i1=csr[e+1];
    u32 v0=hv[(size_t)i0*64+lane], v1=hv[(size_t)i1*64+lane];
    ax+=bflo(v0)+bflo(v1);
    ay+=bfhi(v0)+bfhi(v1);
    e+=2;
  }
  if(e<e1){
    u32 v=hv[(size_t)csr[e]*64+lane];
    ax+=bflo(v); ay+=bfhi(v);
  }
}

// fused setup: zero cur[NBK], prep W->WT bf16, goff binary search
__global__ void k_setup(int* __restrict__ cur,
                        const float* __restrict__ W0, const float* __restrict__ W1,
                        const float* __restrict__ W2, u16* __restrict__ WT,
                        const int* __restrict__ batch, int* __restrict__ goff){
  int i=blockIdx.x*256+threadIdx.x;
  if(i<NBK) cur[i]=0;
  if(i<3*DF*DF){
    int w=i>>14, r=i&16383;
    const float* W = (w==0)?W0:((w==1)?W1:W2);
    int k=r>>7, n=r&127;
    WT[(size_t)w*DF*DF + n*128+k]=f2bf(W[r]);
  }
  if(i<=NG){
    int lo=0, hi=NN;
    while(lo<hi){ int mid=(lo+hi)>>1; if(batch[mid]<i) lo=mid+1; else hi=mid; }
    goff[i]=lo;
  }
}

// partition edges into 256 dst-range buckets; NO per-edge global atomics
__global__ __launch_bounds__(256) void k_part(const int* __restrict__ esrc, const int* __restrict__ edst,
                                              int* __restrict__ cur, uint2* __restrict__ pairs, int n){
  __shared__ int hist[NBK], basev[NBK], lscan[NBK], lcur[NBK];
  __shared__ uint2 stage[PCH];   // 32 KB
  int tid=threadIdx.x;
  int start=blockIdx.x*PCH, end=min(start+PCH,n);
  if(tid<NBK) hist[tid]=0;
  __syncthreads();
  for(int i=start+tid;i<end;i+=256) atomicAdd(&hist[(u32)edst[i]/NPBN],1);
  __syncthreads();
  if(tid<64){
    int carry=0;
    #pragma unroll
    for(int c=0;c<NBK;c+=64){
      int v=hist[c+tid], x=v;
      #pragma unroll
      for(int off=1;off<64;off<<=1){ int t=__shfl_up(x,off,64); if(tid>=off) x+=t; }
      lscan[c+tid]=x-v+carry;
      carry+=__shfl(x,63,64);
    }
  }
  __syncthreads();
  if(tid<NBK){ basev[tid]=atomicAdd(&cur[tid],hist[tid]); lcur[tid]=0; }
  __syncthreads();
  for(int i=start+tid;i<end;i+=256){
    int d=edst[i], s=esrc[i];
    int b=(u32)d/NPBN;
    int p=lscan[b]+atomicAdd(&lcur[b],1);
    stage[p]=make_uint2((u32)s,(u32)d);
  }
  __syncthreads();
  int ntot=end-start;
  for(int i=tid;i<ntot;i+=256){
    uint2 e=stage[i];
    int b=(u32)e.y/NPBN;
    pairs[(size_t)b*BKCAP + basev[b] + (i - lscan[b])]=e;
  }
}

// one block per bucket: local histogram -> offs/dinv -> place csr (L2-local window)
__global__ __launch_bounds__(256) void k_bucket(const uint2* __restrict__ pairs, const int* __restrict__ cur,
                                                int* __restrict__ offs, float* __restrict__ dinv,
                                                int* __restrict__ csr){
  __shared__ int hist[NPBN], lsc[NPBN], curL[NBK];
  __shared__ int sbase[2];
  int b=blockIdx.x, tid=threadIdx.x;
  if(tid<NBK) curL[tid]=cur[tid];
  for(int j=tid;j<NPBN;j+=256) hist[j]=0;
  __syncthreads();
  if(tid<64){
    int acc=0;
    #pragma unroll
    for(int c=0;c<NBK;c+=64){
      int v=(c+tid<b)? curL[c+tid] : 0;
      #pragma unroll
      for(int off=32;off;off>>=1) v+=__shfl_xor(v,off,64);
      acc+=v;
    }
    if(tid==0){ sbase[0]=acc; sbase[1]=curL[b]; }
  }
  __syncthreads();
  int base=sbase[0], count=sbase[1];
  int node0=b*NPBN;
  int nnode=min(NPBN, NN-node0);
  const uint2* P=pairs+(size_t)b*BKCAP;
  for(int i=tid;i<count;i+=256) atomicAdd(&hist[P[i].y-node0],1);
  __syncthreads();
  if(tid<64){
    int carry=0;
    #pragma unroll
    for(int c=0;c<448;c+=64){
      int idx=c+tid;
      int v=(idx<NPBN)? hist[idx] : 0, x=v;
      #pragma unroll
      for(int off=1;off<64;off<<=1){ int t=__shfl_up(x,off,64); if(tid>=off) x+=t; }
      if(idx<NPBN) lsc[idx]=x-v+carry;
      carry+=__shfl(x,63,64);
    }
  }
  __syncthreads();
  for(int j=tid;j<nnode;j+=256){
    offs[node0+j]=base+lsc[j];
    dinv[node0+j]=rsqrtf((float)hist[j]+1.0f);
  }
  if(b==NBK-1 && tid==0) offs[NN]=base+count;
  __syncthreads();
  for(int j=tid;j<nnode;j+=256) hist[j]=lsc[j];
  __syncthreads();
  for(int i=tid;i<count;i+=256){
    uint2 e=P[i];
    int p=atomicAdd(&hist[e.y-node0],1);
    csr[base+p]=(int)e.x;
  }
}

// out[row][c] = bf16( dinv[row] * sum_k A[row][k]*W[k][c] ), MFMA bf16, 512 threads
template<bool F32IN>
__global__ __launch_bounds__(512) void k_gemm(const void* __restrict__ Ap, const u16* __restrict__ WT,
                                              const float* __restrict__ dinv, u16* __restrict__ outp, int n){
  __shared__ u16 sA[128][136];   // row stride 272B
  __shared__ u16 sW[128][136];   // W^T: sW[n][k]
  int tid=threadIdx.x;
  int row0=blockIdx.x*128;
  {
    const uint4* p=(const uint4*)WT;
    #pragma unroll
    for(int j=0;j<4;++j){
      int c=tid+j*512;             // 2048 chunks of 8 bf16
      int r=c>>4, c8=c&15;
      *(uint4*)&sW[r][c8*8]=p[c];
    }
  }
  if(F32IN){
    const float4* A4=(const float4*)Ap;
    #pragma unroll
    for(int j=0;j<8;++j){
      int c=tid+j*512;             // 4096 chunks of 4 floats
      int r=c>>5, c4=c&31;
      int row=row0+r;
      float4 v = (row<n)? A4[(size_t)row*32+c4] : make_float4(0.f,0.f,0.f,0.f);
      u32 lo=(u32)f2bf(v.x) | ((u32)f2bf(v.y)<<16);
      u32 hi=(u32)f2bf(v.z) | ((u32)f2bf(v.w)<<16);
      uint2 q; q.x=lo; q.y=hi;
      *(uint2*)&sA[r][c4*4]=q;
    }
  } else {
    const uint4* A4=(const uint4*)Ap;
    #pragma unroll
    for(int j=0;j<4;++j){
      int c=tid+j*512;             // 2048 chunks of 8 bf16
      int r=c>>4, c8=c&15;
      int row=row0+r;
      uint4 v = (row<n)? A4[(size_t)row*16+c8] : make_uint4(0,0,0,0);
      *(uint4*)&sA[r][c8*8]=v;
    }
  }
  __syncthreads();
  // 8 waves; wave wid owns rows [wid*16, wid*16+16)
  int wid=tid>>6, lane=tid&63;
  int lr=lane&15, lk=lane>>4;
  f32x4 acc[8];
  #pragma unroll
  for(int nt=0;nt<8;++nt) acc[nt]=(f32x4){0.f,0.f,0.f,0.f};
  #pragma unroll
  for(int kk=0;kk<4;++kk){
    bf16x8 a=*(const bf16x8*)&sA[wid*16+lr][kk*32+lk*8];
    bf16x8 b[8];
    #pragma unroll
    for(int nt=0;nt<8;++nt)
      b[nt]=*(const bf16x8*)&sW[nt*16+lr][kk*32+lk*8];
    #pragma unroll
    for(int nt=0;nt<8;++nt)
      acc[nt]=__builtin_amdgcn_mfma_f32_16x16x32_bf16(a,b[nt],acc[nt],0,0,0);
  }
  int rbase=row0+wid*16+lk*4;
  #pragma unroll
  for(int r=0;r<4;++r){
    int row=rbase+r;
    if(row<n){
      float di=dinv[row];
      #pragma unroll
      for(int nt=0;nt<8;++nt)
        outp[(size_t)row*128+nt*16+lr]=f2bf(acc[nt][r]*di);
    }
  }
}

// aggregation: out = bf16(relu(dinv*(gather)+b)), wave per node
__global__ __launch_bounds__(256) void k_agg(const u16* __restrict__ h2, const int* __restrict__ offs,
                                             const int* __restrict__ csr, const float* __restrict__ dinv,
                                             const float* __restrict__ bias, u16* __restrict__ outp, int n){
  int wid=threadIdx.x>>6, lane=threadIdx.x&63;
  int node=blockIdx.x*4+wid;
  if(node>=n) return;
  const u32* hv=(const u32*)h2;
  u32 sv=hv[(size_t)node*64+lane];
  float ax=bflo(sv), ay=bfhi(sv);
  agg_node(hv, csr, offs[node], offs[node+1], lane, ax, ay);
  float di=dinv[node];
  float2 b=*(const float2*)&bias[lane*2];
  float ox=fmaf(di,ax,b.x), oy=fmaf(di,ay,b.y);
  ox=ox>0.f?ox:0.f; oy=oy>0.f?oy:0.f;
  u32 o=(u32)f2bf(ox) | ((u32)f2bf(oy)<<16);
  ((u32*)outp)[(size_t)node*64+lane]=o;
}

// 8-wave pooling: wave w strides rows, lane loads u32 (2 cols); LDS reduce + matvec
__global__ __launch_bounds__(512) void k_pool(const u16* __restrict__ h, const int* __restrict__ goff,
                                              const float* __restrict__ Wc, const float* __restrict__ bc,
                                              float* __restrict__ outp){
  __shared__ float part[8][128];
  __shared__ float pooled[128];
  int g=blockIdx.x;
  int tid=threadIdx.x, wid=tid>>6, lane=tid&63;
  int i0=goff[g], i1=goff[g+1];
  const u32* hv=(const u32*)h;
  float ax=0.f, ay=0.f;
  for(int i=i0+wid;i<i1;i+=8){
    u32 v=hv[(size_t)i*64+lane];
    ax+=bflo(v); ay+=bfhi(v);
  }
  part[wid][lane*2]=ax; part[wid][lane*2+1]=ay;
  __syncthreads();
  if(tid<128){
    float s=part[0][tid]+part[1][tid]+part[2][tid]+part[3][tid]
           +part[4][tid]+part[5][tid]+part[6][tid]+part[7][tid];
    int cnt=i1-i0;
    pooled[tid]=(cnt>0)? s/(float)cnt : 0.f;
  }
  __syncthreads();
  if(tid<NC){
    float s=bc[tid];
    #pragma unroll 16
    for(int k=0;k<128;++k) s=fmaf(pooled[k], Wc[k*NC+tid], s);
    outp[g*NC+tid]=s;
  }
}

extern "C" void kernel_launch(void* const* d_in, const int* in_sizes, int n_in,
                              void* d_out, int out_size, void* d_ws, size_t ws_size,
                              hipStream_t stream){
  const float* x   =(const float*)d_in[0];
  const int* esrc  =(const int*)d_in[1];
  const int* edst  =(const int*)d_in[2];
  const int* batch =(const int*)d_in[3];
  const float* W0=(const float*)d_in[4];
  const float* b0=(const float*)d_in[5];
  const float* W1=(const float*)d_in[6];
  const float* b1=(const float*)d_in[7];
  const float* W2=(const float*)d_in[8];
  const float* b2=(const float*)d_in[9];
  const float* Wc=(const float*)d_in[10];
  const float* bc=(const float*)d_in[11];
  float* out=(float*)d_out;

  char* base=(char*)d_ws; size_t off=0;
  auto alloc=[&](size_t bytes)->void*{ off=(off+255)&~(size_t)255; void* p=base+off; off+=bytes; return p; };
  int*   cur  =(int*)  alloc(NBK*4);
  int*   offs =(int*)  alloc((size_t)(NN+1)*4);
  int*   goff =(int*)  alloc((NG+1)*4);
  float* dinv =(float*)alloc((size_t)NN*4);
  int*   csr  =(int*)  alloc((size_t)NE*4);
  uint2* pairs=(uint2*)alloc((size_t)NBK*BKCAP*8);
  u16*   WT   =(u16*)  alloc((size_t)3*DF*DF*2);
  u16*   bufA =(u16*)  alloc((size_t)NN*DF*2);
  u16*   bufB =(u16*)  alloc((size_t)NN*DF*2);
  (void)ws_size; (void)in_sizes; (void)n_in; (void)out_size;

  hipLaunchKernelGGL(k_setup,  dim3(192),  dim3(256), 0, stream, cur, W0, W1, W2, WT, batch, goff);
  hipLaunchKernelGGL(k_part,   dim3((NE+PCH-1)/PCH), dim3(256), 0, stream, esrc, edst, cur, pairs, NE);
  hipLaunchKernelGGL(k_bucket, dim3(NBK),  dim3(256), 0, stream, pairs, cur, offs, dinv, csr);

  const int GB=(NN+127)/128;    // 782
  const int AB=(NN+3)/4;        // 25000

  k_gemm<true ><<<dim3(GB), dim3(512), 0, stream>>>((const void*)x,    WT,         dinv, bufA, NN);
  hipLaunchKernelGGL(k_agg,  dim3(AB), dim3(256), 0, stream, bufA, offs, csr, dinv, b0, bufB, NN);
  k_gemm<false><<<dim3(GB), dim3(512), 0, stream>>>((const void*)bufB, WT+DF*DF,   dinv, bufA, NN);
  hipLaunchKernelGGL(k_agg,  dim3(AB), dim3(256), 0, stream, bufA, offs, csr, dinv, b1, bufB, NN);
  k_gemm<false><<<dim3(GB), dim3(512), 0, stream>>>((const void*)bufB, WT+2*DF*DF, dinv, bufA, NN);
  hipLaunchKernelGGL(k_agg,  dim3(AB), dim3(256), 0, stream, bufA, offs, csr, dinv, b2, bufB, NN);
  hipLaunchKernelGGL(k_pool, dim3(NG), dim3(512), 0, stream, bufB, goff, Wc, bc, out);
}

// Round 13
// 290.413 us; speedup vs baseline: 1.2027x; 1.0313x over previous
//
#include <hip/hip_runtime.h>

#define NN 100000
#define NE 1600000
#define DF 128
#define NG 512
#define NC 10
#define NBK 256
#define NPBN 391       // nodes per bucket = ceil(NN/NBK)
#define BKCAP 8192     // pairs capacity per bucket (mean 6250, sigma ~79)
#define PCH 8192       // edges per partition block (512 threads)

typedef unsigned short u16;
typedef unsigned int u32;
typedef __bf16 bf16_t;
typedef bf16_t bf16x8 __attribute__((ext_vector_type(8)));
typedef float f32x4 __attribute__((ext_vector_type(4)));

__device__ __forceinline__ u16 f2bf(float f){
  u32 x=__float_as_uint(f);
  u32 r=(x+0x7fffu+((x>>16)&1u))>>16;
  return (u16)r;
}
__device__ __forceinline__ float bflo(u32 u){ return __uint_as_float(u<<16); }
__device__ __forceinline__ float bfhi(u32 u){ return __uint_as_float(u&0xffff0000u); }

// gather-aggregate one node's neighbor rows (lane holds 2 cols as u32)
__device__ __forceinline__ void agg_node(const u32* __restrict__ hv, const int* __restrict__ csr,
                                         int e, int e1, int lane, float& ax, float& ay){
  for(; e+16<=e1; e+=16){
    int ii[16];
    #pragma unroll
    for(int j=0;j<16;++j) ii[j]=csr[e+j];
    u32 vv[16];
    #pragma unroll
    for(int j=0;j<16;++j) vv[j]=hv[(size_t)ii[j]*64+lane];
    #pragma unroll
    for(int j=0;j<16;++j){ ax+=bflo(vv[j]); ay+=bfhi(vv[j]); }
  }
  if(e+8<=e1){
    int ii[8];
    #pragma unroll
    for(int j=0;j<8;++j) ii[j]=csr[e+j];
    u32 vv[8];
    #pragma unroll
    for(int j=0;j<8;++j) vv[j]=hv[(size_t)ii[j]*64+lane];
    #pragma unroll
    for(int j=0;j<8;++j){ ax+=bflo(vv[j]); ay+=bfhi(vv[j]); }
    e+=8;
  }
  if(e+4<=e1){
    int i0=csr[e],i1=csr[e+1],i2=csr[e+2],i3=csr[e+3];
    u32 v0=hv[(size_t)i0*64+lane], v1=hv[(size_t)i1*64+lane];
    u32 v2=hv[(size_t)i2*64+lane], v3=hv[(size_t)i3*64+lane];
    ax+=bflo(v0)+bflo(v1)+bflo(v2)+bflo(v3);
    ay+=bfhi(v0)+bfhi(v1)+bfhi(v2)+bfhi(v3);
    e+=4;
  }
  if(e+2<=e1){
    int i0=csr[e],i1=csr[e+1];
    u32 v0=hv[(size_t)i0*64+lane], v1=hv[(size_t)i1*64+lane];
    ax+=bflo(v0)+bflo(v1);
    ay+=bfhi(v0)+bfhi(v1);
    e+=2;
  }
  if(e<e1){
    u32 v=hv[(size_t)csr[e]*64+lane];
    ax+=bflo(v); ay+=bfhi(v);
  }
}

// fused setup: zero cur[NBK], prep W->WT bf16, goff binary search
__global__ void k_setup(int* __restrict__ cur,
                        const float* __restrict__ W0, const float* __restrict__ W1,
                        const float* __restrict__ W2, u16* __restrict__ WT,
                        const int* __restrict__ batch, int* __restrict__ goff){
  int i=blockIdx.x*256+threadIdx.x;
  if(i<NBK) cur[i]=0;
  if(i<3*DF*DF){
    int w=i>>14, r=i&16383;
    const float* W = (w==0)?W0:((w==1)?W1:W2);
    int k=r>>7, n=r&127;
    WT[(size_t)w*DF*DF + n*128+k]=f2bf(W[r]);
  }
  if(i<=NG){
    int lo=0, hi=NN;
    while(lo<hi){ int mid=(lo+hi)>>1; if(batch[mid]<i) lo=mid+1; else hi=mid; }
    goff[i]=lo;
  }
}

// partition edges into 256 dst-range buckets; NO per-edge global atomics (512 thr)
__global__ __launch_bounds__(512) void k_part(const int* __restrict__ esrc, const int* __restrict__ edst,
                                              int* __restrict__ cur, uint2* __restrict__ pairs, int n){
  __shared__ int hist[NBK], basev[NBK], lscan[NBK], lcur[NBK];
  __shared__ uint2 stage[PCH];   // 64 KB
  int tid=threadIdx.x;
  int start=blockIdx.x*PCH, end=min(start+PCH,n);
  if(tid<NBK) hist[tid]=0;
  __syncthreads();
  for(int i=start+tid;i<end;i+=512) atomicAdd(&hist[(u32)edst[i]/NPBN],1);
  __syncthreads();
  if(tid<64){
    int carry=0;
    #pragma unroll
    for(int c=0;c<NBK;c+=64){
      int v=hist[c+tid], x=v;
      #pragma unroll
      for(int off=1;off<64;off<<=1){ int t=__shfl_up(x,off,64); if(tid>=off) x+=t; }
      lscan[c+tid]=x-v+carry;
      carry+=__shfl(x,63,64);
    }
  }
  __syncthreads();
  if(tid<NBK){ basev[tid]=atomicAdd(&cur[tid],hist[tid]); lcur[tid]=0; }
  __syncthreads();
  for(int i=start+tid;i<end;i+=512){
    int d=edst[i], s=esrc[i];
    int b=(u32)d/NPBN;
    int p=lscan[b]+atomicAdd(&lcur[b],1);
    stage[p]=make_uint2((u32)s,(u32)d);
  }
  __syncthreads();
  int ntot=end-start;
  for(int i=tid;i<ntot;i+=512){
    uint2 e=stage[i];
    int b=(u32)e.y/NPBN;
    pairs[(size_t)b*BKCAP + basev[b] + (i - lscan[b])]=e;
  }
}

// one block per bucket: local histogram -> offs/dinv -> place csr (512 thr)
__global__ __launch_bounds__(512) void k_bucket(const uint2* __restrict__ pairs, const int* __restrict__ cur,
                                                int* __restrict__ offs, float* __restrict__ dinv,
                                                int* __restrict__ csr){
  __shared__ int hist[NPBN], lsc[NPBN], curL[NBK];
  __shared__ int sbase[2];
  int b=blockIdx.x, tid=threadIdx.x;
  if(tid<NBK) curL[tid]=cur[tid];
  for(int j=tid;j<NPBN;j+=512) hist[j]=0;
  __syncthreads();
  if(tid<64){
    int acc=0;
    #pragma unroll
    for(int c=0;c<NBK;c+=64){
      int v=(c+tid<b)? curL[c+tid] : 0;
      #pragma unroll
      for(int off=32;off;off>>=1) v+=__shfl_xor(v,off,64);
      acc+=v;
    }
    if(tid==0){ sbase[0]=acc; sbase[1]=curL[b]; }
  }
  __syncthreads();
  int base=sbase[0], count=sbase[1];
  int node0=b*NPBN;
  int nnode=min(NPBN, NN-node0);
  const uint2* P=pairs+(size_t)b*BKCAP;
  for(int i=tid;i<count;i+=512) atomicAdd(&hist[P[i].y-node0],1);
  __syncthreads();
  if(tid<64){
    int carry=0;
    #pragma unroll
    for(int c=0;c<448;c+=64){
      int idx=c+tid;
      int v=(idx<NPBN)? hist[idx] : 0, x=v;
      #pragma unroll
      for(int off=1;off<64;off<<=1){ int t=__shfl_up(x,off,64); if(tid>=off) x+=t; }
      if(idx<NPBN) lsc[idx]=x-v+carry;
      carry+=__shfl(x,63,64);
    }
  }
  __syncthreads();
  for(int j=tid;j<nnode;j+=512){
    offs[node0+j]=base+lsc[j];
    dinv[node0+j]=rsqrtf((float)hist[j]+1.0f);
  }
  if(b==NBK-1 && tid==0) offs[NN]=base+count;
  __syncthreads();
  for(int j=tid;j<nnode;j+=512) hist[j]=lsc[j];
  __syncthreads();
  for(int i=tid;i<count;i+=512){
    uint2 e=P[i];
    int p=atomicAdd(&hist[e.y-node0],1);
    csr[base+p]=(int)e.x;
  }
}

// out[row][c] = bf16( dinv[row] * sum_k A[row][k]*W[k][c] ), MFMA bf16, 512 threads
template<bool F32IN>
__global__ __launch_bounds__(512) void k_gemm(const void* __restrict__ Ap, const u16* __restrict__ WT,
                                              const float* __restrict__ dinv, u16* __restrict__ outp, int n){
  __shared__ u16 sA[128][136];   // row stride 272B
  __shared__ u16 sW[128][136];   // W^T: sW[n][k]
  int tid=threadIdx.x;
  int row0=blockIdx.x*128;
  {
    const uint4* p=(const uint4*)WT;
    #pragma unroll
    for(int j=0;j<4;++j){
      int c=tid+j*512;
      int r=c>>4, c8=c&15;
      *(uint4*)&sW[r][c8*8]=p[c];
    }
  }
  if(F32IN){
    const float4* A4=(const float4*)Ap;
    #pragma unroll
    for(int j=0;j<8;++j){
      int c=tid+j*512;
      int r=c>>5, c4=c&31;
      int row=row0+r;
      float4 v = (row<n)? A4[(size_t)row*32+c4] : make_float4(0.f,0.f,0.f,0.f);
      u32 lo=(u32)f2bf(v.x) | ((u32)f2bf(v.y)<<16);
      u32 hi=(u32)f2bf(v.z) | ((u32)f2bf(v.w)<<16);
      uint2 q; q.x=lo; q.y=hi;
      *(uint2*)&sA[r][c4*4]=q;
    }
  } else {
    const uint4* A4=(const uint4*)Ap;
    #pragma unroll
    for(int j=0;j<4;++j){
      int c=tid+j*512;
      int r=c>>4, c8=c&15;
      int row=row0+r;
      uint4 v = (row<n)? A4[(size_t)row*16+c8] : make_uint4(0,0,0,0);
      *(uint4*)&sA[r][c8*8]=v;
    }
  }
  __syncthreads();
  int wid=tid>>6, lane=tid&63;
  int lr=lane&15, lk=lane>>4;
  f32x4 acc[8];
  #pragma unroll
  for(int nt=0;nt<8;++nt) acc[nt]=(f32x4){0.f,0.f,0.f,0.f};
  #pragma unroll
  for(int kk=0;kk<4;++kk){
    bf16x8 a=*(const bf16x8*)&sA[wid*16+lr][kk*32+lk*8];
    bf16x8 b[8];
    #pragma unroll
    for(int nt=0;nt<8;++nt)
      b[nt]=*(const bf16x8*)&sW[nt*16+lr][kk*32+lk*8];
    #pragma unroll
    for(int nt=0;nt<8;++nt)
      acc[nt]=__builtin_amdgcn_mfma_f32_16x16x32_bf16(a,b[nt],acc[nt],0,0,0);
  }
  int rbase=row0+wid*16+lk*4;
  #pragma unroll
  for(int r=0;r<4;++r){
    int row=rbase+r;
    if(row<n){
      float di=dinv[row];
      #pragma unroll
      for(int nt=0;nt<8;++nt)
        outp[(size_t)row*128+nt*16+lr]=f2bf(acc[nt][r]*di);
    }
  }
}

// aggregation: out = bf16(relu(dinv*(gather)+b)), wave per node
__global__ __launch_bounds__(256) void k_agg(const u16* __restrict__ h2, const int* __restrict__ offs,
                                             const int* __restrict__ csr, const float* __restrict__ dinv,
                                             const float* __restrict__ bias, u16* __restrict__ outp, int n){
  int wid=threadIdx.x>>6, lane=threadIdx.x&63;
  int node=blockIdx.x*4+wid;
  if(node>=n) return;
  const u32* hv=(const u32*)h2;
  u32 sv=hv[(size_t)node*64+lane];
  float ax=bflo(sv), ay=bfhi(sv);
  agg_node(hv, csr, offs[node], offs[node+1], lane, ax, ay);
  float di=dinv[node];
  float2 b=*(const float2*)&bias[lane*2];
  float ox=fmaf(di,ax,b.x), oy=fmaf(di,ay,b.y);
  ox=ox>0.f?ox:0.f; oy=oy>0.f?oy:0.f;
  u32 o=(u32)f2bf(ox) | ((u32)f2bf(oy)<<16);
  ((u32*)outp)[(size_t)node*64+lane]=o;
}

// 8-wave pooling + classifier head
__global__ __launch_bounds__(512) void k_pool(const u16* __restrict__ h, const int* __restrict__ goff,
                                              const float* __restrict__ Wc, const float* __restrict__ bc,
                                              float* __restrict__ outp){
  __shared__ float part[8][128];
  __shared__ float pooled[128];
  int g=blockIdx.x;
  int tid=threadIdx.x, wid=tid>>6, lane=tid&63;
  int i0=goff[g], i1=goff[g+1];
  const u32* hv=(const u32*)h;
  float ax=0.f, ay=0.f;
  for(int i=i0+wid;i<i1;i+=8){
    u32 v=hv[(size_t)i*64+lane];
    ax+=bflo(v); ay+=bfhi(v);
  }
  part[wid][lane*2]=ax; part[wid][lane*2+1]=ay;
  __syncthreads();
  if(tid<128){
    float s=part[0][tid]+part[1][tid]+part[2][tid]+part[3][tid]
           +part[4][tid]+part[5][tid]+part[6][tid]+part[7][tid];
    int cnt=i1-i0;
    pooled[tid]=(cnt>0)? s/(float)cnt : 0.f;
  }
  __syncthreads();
  if(tid<NC){
    float s=bc[tid];
    #pragma unroll 16
    for(int k=0;k<128;++k) s=fmaf(pooled[k], Wc[k*NC+tid], s);
    outp[g*NC+tid]=s;
  }
}

extern "C" void kernel_launch(void* const* d_in, const int* in_sizes, int n_in,
                              void* d_out, int out_size, void* d_ws, size_t ws_size,
                              hipStream_t stream){
  const float* x   =(const float*)d_in[0];
  const int* esrc  =(const int*)d_in[1];
  const int* edst  =(const int*)d_in[2];
  const int* batch =(const int*)d_in[3];
  const float* W0=(const float*)d_in[4];
  const float* b0=(const float*)d_in[5];
  const float* W1=(const float*)d_in[6];
  const float* b1=(const float*)d_in[7];
  const float* W2=(const float*)d_in[8];
  const float* b2=(const float*)d_in[9];
  const float* Wc=(const float*)d_in[10];
  const float* bc=(const float*)d_in[11];
  float* out=(float*)d_out;

  char* base=(char*)d_ws; size_t off=0;
  auto alloc=[&](size_t bytes)->void*{ off=(off+255)&~(size_t)255; void* p=base+off; off+=bytes; return p; };
  int*   cur  =(int*)  alloc(NBK*4);
  int*   offs =(int*)  alloc((size_t)(NN+1)*4);
  int*   goff =(int*)  alloc((NG+1)*4);
  float* dinv =(float*)alloc((size_t)NN*4);
  int*   csr  =(int*)  alloc((size_t)NE*4);
  uint2* pairs=(uint2*)alloc((size_t)NBK*BKCAP*8);
  u16*   WT   =(u16*)  alloc((size_t)3*DF*DF*2);
  u16*   bufA =(u16*)  alloc((size_t)NN*DF*2);
  u16*   bufB =(u16*)  alloc((size_t)NN*DF*2);
  (void)ws_size; (void)in_sizes; (void)n_in; (void)out_size;

  hipLaunchKernelGGL(k_setup,  dim3(192),  dim3(256), 0, stream, cur, W0, W1, W2, WT, batch, goff);
  hipLaunchKernelGGL(k_part,   dim3((NE+PCH-1)/PCH), dim3(512), 0, stream, esrc, edst, cur, pairs, NE);
  hipLaunchKernelGGL(k_bucket, dim3(NBK),  dim3(512), 0, stream, pairs, cur, offs, dinv, csr);

  const int GB=(NN+127)/128;    // 782
  const int AB=(NN+3)/4;        // 25000

  k_gemm<true ><<<dim3(GB), dim3(512), 0, stream>>>((const void*)x,    WT,         dinv, bufA, NN);
  hipLaunchKernelGGL(k_agg,  dim3(AB), dim3(256), 0, stream, bufA, offs, csr, dinv, b0, bufB, NN);
  k_gemm<false><<<dim3(GB), dim3(512), 0, stream>>>((const void*)bufB, WT+DF*DF,   dinv, bufA, NN);
  hipLaunchKernelGGL(k_agg,  dim3(AB), dim3(256), 0, stream, bufA, offs, csr, dinv, b1, bufB, NN);
  k_gemm<false><<<dim3(GB), dim3(512), 0, stream>>>((const void*)bufB, WT+2*DF*DF, dinv, bufA, NN);
  hipLaunchKernelGGL(k_agg,  dim3(AB), dim3(256), 0, stream, bufA, offs, csr, dinv, b2, bufB, NN);
  hipLaunchKernelGGL(k_pool, dim3(NG), dim3(512), 0, stream, bufB, goff, Wc, bc, out);
}